// Round 1
// baseline (9248.594 us; speedup 1.0000x reference)
//
#include <hip/hip_runtime.h>
#include <hip/hip_bf16.h>
#include <stdint.h>

// Decoder: 2-layer LSTM, B=2048, T=96, H=1024, teacher forcing=1.0.
// Round 1: bf16-MFMA per-step GEMMs (m97-style 128x128 tile), separate cell kernels.
// ws usage ~104.5 MB.

#define BB  2048
#define TT  96
#define HHH 1024
#define NG  4096      // 4*H
#define KL1 1088      // 64 (x pad) + 1024 (h1)
#define KL2 2048      // h1 | h2
#define LDH 2048      // H12 row stride (bf16 elems)

typedef __bf16 bf16;
typedef __bf16 bf16x8 __attribute__((ext_vector_type(8)));
typedef float  f32x4  __attribute__((ext_vector_type(4)));

__device__ __forceinline__ float sigm(float x) { return 1.0f / (1.0f + __expf(-x)); }

__device__ __forceinline__ void gload16(const bf16* g, bf16* l) {
  __builtin_amdgcn_global_load_lds((const __attribute__((address_space(1))) void*)g,
                                   (__attribute__((address_space(3))) void*)l, 16, 0, 0);
}

// ---------------- prep kernels ----------------

__global__ __launch_bounds__(256) void build_w0(const float* __restrict__ Wih0,
                                                const float* __restrict__ Whh0,
                                                bf16* __restrict__ W0) {
  int idx = blockIdx.x * 256 + threadIdx.x;
  if (idx >= NG * KL1) return;
  int n = idx / KL1, k = idx % KL1;
  float v;
  if (k < 60)       v = Wih0[n * 60 + k];
  else if (k < 64)  v = 0.0f;
  else              v = Whh0[n * 1024 + (k - 64)];
  W0[idx] = (bf16)v;
}

__global__ __launch_bounds__(256) void build_w1(const float* __restrict__ Wih1,
                                                const float* __restrict__ Whh1,
                                                bf16* __restrict__ W1) {
  int idx = blockIdx.x * 256 + threadIdx.x;
  if (idx >= NG * KL2) return;
  int n = idx >> 11, k = idx & 2047;
  float v = (k < 1024) ? Wih1[n * 1024 + k] : Whh1[n * 1024 + (k - 1024)];
  W1[idx] = (bf16)v;
}

__global__ __launch_bounds__(256) void build_x(
    const float* __restrict__ dec, const float* __restrict__ ty, const float* __restrict__ lec,
    const int* __restrict__ gid, const int* __restrict__ cp, const int* __restrict__ cct,
    const int* __restrict__ cpt, const int* __restrict__ ccl,
    const float* __restrict__ gemb, const float* __restrict__ ep, const float* __restrict__ ect,
    const float* __restrict__ ept, const float* __restrict__ ecl,
    bf16* __restrict__ X) {
  int idx = blockIdx.x * 256 + threadIdx.x;  // over B*T
  if (idx >= BB * TT) return;
  int b = idx / TT, t = idx % TT;
  bf16* x = X + (size_t)idx * 64;
  x[0] = (bf16)((t == 0) ? lec[b] : ty[b * TT + t - 1]);
  const float* d = dec + (size_t)idx * 32;
  #pragma unroll
  for (int k = 0; k < 32; ++k) x[1 + k] = (bf16)d[k];
  const float* e;
  e = ep  + cp[b]  * 4;  for (int j = 0; j < 4;  ++j) x[33 + j] = (bf16)e[j];
  e = ect + cct[b] * 2;  for (int j = 0; j < 2;  ++j) x[37 + j] = (bf16)e[j];
  e = ept + cpt[b] * 3;  for (int j = 0; j < 3;  ++j) x[39 + j] = (bf16)e[j];
  e = ecl + ccl[b] * 2;  for (int j = 0; j < 2;  ++j) x[42 + j] = (bf16)e[j];
  e = gemb + gid[b] * 16; for (int j = 0; j < 16; ++j) x[44 + j] = (bf16)e[j];
  for (int j = 60; j < 64; ++j) x[j] = (bf16)0.0f;
}

__global__ __launch_bounds__(256) void init_state(const float* __restrict__ enc_h,
                                                  const float* __restrict__ enc_c,
                                                  bf16* __restrict__ H12,
                                                  float* __restrict__ c1,
                                                  float* __restrict__ c2) {
  int idx = blockIdx.x * 256 + threadIdx.x;  // over B*H
  if (idx >= BB * HHH) return;
  int b = idx >> 10, h = idx & 1023;
  H12[(size_t)b * LDH + h]        = (bf16)enc_h[idx];
  H12[(size_t)b * LDH + 1024 + h] = (bf16)enc_h[(size_t)BB * HHH + idx];
  c1[idx] = enc_c[idx];
  c2[idx] = enc_c[(size_t)BB * HHH + idx];
}

// ---------------- GEMM: gates = A @ W^T + bias ----------------
// MODE 0: A = [X_all[:,t,:64] | H12[:,0:1024]], K=1088, W=W0
// MODE 1: A = H12 (full 2048),                  K=2048, W=W1
// 128x128 tile, BK=32, 256 threads (4 waves, 2x2 of 64x64), mfma 16x16x32 bf16.

template <int MODE>
__global__ __launch_bounds__(256, 2) void gemm_gates(
    const bf16* __restrict__ Ah, const bf16* __restrict__ Ax,
    const bf16* __restrict__ Wt, const float* __restrict__ bias,
    float* __restrict__ gates, int t) {
  constexpr int KT = (MODE == 0) ? KL1 : KL2;
  __shared__ alignas(16) bf16 As[128 * 32];
  __shared__ alignas(16) bf16 Bs[128 * 32];

  int tid = threadIdx.x;
  int bid = blockIdx.x;
  int tm = (bid & 15) << 7;   // 16 M-tiles
  int tn = (bid >> 4) << 7;   // 32 N-tiles
  int lane = tid & 63;
  int w = tid >> 6;
  int wm = (w & 1) << 6, wn = (w >> 1) << 6;

  f32x4 acc[4][4];
  #pragma unroll
  for (int m = 0; m < 4; ++m)
    #pragma unroll
    for (int n = 0; n < 4; ++n) acc[m][n] = (f32x4){0.f, 0.f, 0.f, 0.f};

  // staging geometry: linear element idx = (load*256 + tid)*8; row=lin>>2, kcol=(lin&3)*8
  int r0 = tid >> 2,          kc0 = (tid & 3) << 3;
  int r1 = (256 + tid) >> 2,  kc1 = kc0;  // (256+tid)&3 == tid&3
  bf16* ldsA0 = &As[(tid & ~63) * 8];
  bf16* ldsA1 = &As[(256 + (tid & ~63)) * 8];
  bf16* ldsB0 = &Bs[(tid & ~63) * 8];
  bf16* ldsB1 = &Bs[(256 + (tid & ~63)) * 8];

  int lrow = lane & 15, koff = (lane >> 4) << 3;

  for (int kt = 0; kt < KT / 32; ++kt) {
    int gk0 = kt * 32 + kc0, gk1 = kt * 32 + kc1;
    const bf16 *a0, *a1;
    if constexpr (MODE == 0) {
      a0 = (gk0 < 64) ? (Ax + ((size_t)(tm + r0) * TT + t) * 64 + gk0)
                      : (Ah + (size_t)(tm + r0) * LDH + (gk0 - 64));
      a1 = (gk1 < 64) ? (Ax + ((size_t)(tm + r1) * TT + t) * 64 + gk1)
                      : (Ah + (size_t)(tm + r1) * LDH + (gk1 - 64));
    } else {
      a0 = Ah + (size_t)(tm + r0) * LDH + gk0;
      a1 = Ah + (size_t)(tm + r1) * LDH + gk1;
    }
    const bf16* b0p = Wt + (size_t)(tn + r0) * KT + gk0;
    const bf16* b1p = Wt + (size_t)(tn + r1) * KT + gk1;

    __syncthreads();  // previous compute done; safe to overwrite LDS
    gload16(a0, ldsA0);
    gload16(a1, ldsA1);
    gload16(b0p, ldsB0);
    gload16(b1p, ldsB1);
    __syncthreads();  // vmcnt drained per-wave before barrier -> tiles visible

    bf16x8 af[4], bfr[4];
    #pragma unroll
    for (int m = 0; m < 4; ++m)
      af[m] = *reinterpret_cast<const bf16x8*>(&As[(wm + m * 16 + lrow) * 32 + koff]);
    #pragma unroll
    for (int n = 0; n < 4; ++n)
      bfr[n] = *reinterpret_cast<const bf16x8*>(&Bs[(wn + n * 16 + lrow) * 32 + koff]);
    #pragma unroll
    for (int m = 0; m < 4; ++m)
      #pragma unroll
      for (int n = 0; n < 4; ++n)
        acc[m][n] = __builtin_amdgcn_mfma_f32_16x16x32_bf16(af[m], bfr[n], acc[m][n], 0, 0, 0);
  }

  // epilogue: D mapping col=lane&15 (N), row=(lane>>4)*4+reg (M)  [m89-verified]
  int orow = (lane >> 4) << 2;
  int ocol = lane & 15;
  #pragma unroll
  for (int n = 0; n < 4; ++n) {
    int gcol = tn + wn + n * 16 + ocol;
    float bv = bias[gcol];
    #pragma unroll
    for (int m = 0; m < 4; ++m) {
      int grow = tm + wm + m * 16 + orow;
      float* gp = gates + (size_t)grow * NG + gcol;
      #pragma unroll
      for (int r = 0; r < 4; ++r) gp[(size_t)r * NG] = acc[m][n][r] + bv;
    }
  }
}

// ---------------- cell kernels ----------------

__global__ __launch_bounds__(256) void cell1_k(const float* __restrict__ gates,
                                               float* __restrict__ c1,
                                               bf16* __restrict__ H12) {
  int idx = blockIdx.x * 256 + threadIdx.x;  // B*H exactly
  int b = idx >> 10, h = idx & 1023;
  const float* g = gates + (size_t)b * NG;
  float gi = g[h], gf = g[h + 1024], gg = g[h + 2048], go = g[h + 3072];
  float c = c1[idx];
  float cn = sigm(gf) * c + sigm(gi) * tanhf(gg);
  float hn = sigm(go) * tanhf(cn);
  c1[idx] = cn;
  H12[(size_t)b * LDH + h] = (bf16)hn;
}

__global__ __launch_bounds__(1024) void cell2_k(const float* __restrict__ gates,
                                                float* __restrict__ c2,
                                                bf16* __restrict__ H12,
                                                const float* __restrict__ wp,
                                                const float* __restrict__ bp,
                                                float* __restrict__ y, int t) {
  int b = blockIdx.x, h = threadIdx.x;
  const float* g = gates + (size_t)b * NG;
  float gi = g[h], gf = g[h + 1024], gg = g[h + 2048], go = g[h + 3072];
  int idx = b * 1024 + h;
  float c = c2[idx];
  float cn = sigm(gf) * c + sigm(gi) * tanhf(gg);
  float hn = sigm(go) * tanhf(cn);
  c2[idx] = cn;
  H12[(size_t)b * LDH + 1024 + h] = (bf16)hn;

  float p = hn * wp[h];
  #pragma unroll
  for (int off = 32; off > 0; off >>= 1) p += __shfl_down(p, off);
  __shared__ float red[16];
  if ((h & 63) == 0) red[h >> 6] = p;
  __syncthreads();
  if (h == 0) {
    float s = 0.f;
    #pragma unroll
    for (int i = 0; i < 16; ++i) s += red[i];
    y[(size_t)b * TT + t] = s + bp[0];
  }
}

// ---------------- launch ----------------

extern "C" void kernel_launch(void* const* d_in, const int* in_sizes, int n_in,
                              void* d_out, int out_size, void* d_ws, size_t ws_size,
                              hipStream_t stream) {
  const float* dec   = (const float*)d_in[0];
  const float* ty    = (const float*)d_in[1];
  const float* enc_h = (const float*)d_in[2];
  const float* enc_c = (const float*)d_in[3];
  const float* lec   = (const float*)d_in[4];
  const int*   gid   = (const int*)d_in[5];
  const int*   cp    = (const int*)d_in[6];
  const int*   cct   = (const int*)d_in[7];
  const int*   cpt   = (const int*)d_in[8];
  const int*   ccl   = (const int*)d_in[9];
  const float* gemb  = (const float*)d_in[10];
  const float* ep    = (const float*)d_in[11];
  const float* ect   = (const float*)d_in[12];
  const float* ept   = (const float*)d_in[13];
  const float* ecl   = (const float*)d_in[14];
  const float* Wih0  = (const float*)d_in[15];
  const float* Whh0  = (const float*)d_in[16];
  const float* b0    = (const float*)d_in[17];
  const float* Wih1  = (const float*)d_in[18];
  const float* Whh1  = (const float*)d_in[19];
  const float* b1    = (const float*)d_in[20];
  const float* wp    = (const float*)d_in[21];
  const float* bp    = (const float*)d_in[22];
  float* y = (float*)d_out;

  char* ws = (char*)d_ws;
  bf16* W0    = (bf16*)ws;  ws += (size_t)NG * KL1 * 2;   //  8.9 MB
  bf16* W1    = (bf16*)ws;  ws += (size_t)NG * KL2 * 2;   // 16.8 MB
  bf16* X     = (bf16*)ws;  ws += (size_t)BB * TT * 64 * 2; // 25.2 MB
  bf16* H12   = (bf16*)ws;  ws += (size_t)BB * LDH * 2;   //  8.4 MB
  float* c1   = (float*)ws; ws += (size_t)BB * HHH * 4;   //  8.4 MB
  float* c2   = (float*)ws; ws += (size_t)BB * HHH * 4;   //  8.4 MB
  float* gates = (float*)ws;                              // 33.5 MB (shared by both layers)

  build_w0<<<(NG * KL1 + 255) / 256, 256, 0, stream>>>(Wih0, Whh0, W0);
  build_w1<<<(NG * KL2 + 255) / 256, 256, 0, stream>>>(Wih1, Whh1, W1);
  build_x<<<(BB * TT + 255) / 256, 256, 0, stream>>>(dec, ty, lec, gid, cp, cct, cpt, ccl,
                                                     gemb, ep, ect, ept, ecl, X);
  init_state<<<(BB * HHH) / 256, 256, 0, stream>>>(enc_h, enc_c, H12, c1, c2);

  for (int t = 0; t < TT; ++t) {
    gemm_gates<0><<<512, 256, 0, stream>>>(H12, X, W0, b0, gates, t);
    cell1_k<<<(BB * HHH) / 256, 256, 0, stream>>>(gates, c1, H12);
    gemm_gates<1><<<512, 256, 0, stream>>>(H12, nullptr, W1, b1, gates, 0);
    cell2_k<<<BB, 1024, 0, stream>>>(gates, c2, H12, wp, bp, y, t);
  }
}

// Round 2
// 8623.053 us; speedup vs baseline: 1.0725x; 1.0725x over previous
//
#include <hip/hip_runtime.h>
#include <hip/hip_bf16.h>
#include <stdint.h>

// Decoder: 2-layer LSTM, B=2048, T=96, H=1024, teacher forcing=1.0.
// Round 2: cells + proj fused into GEMM epilogues via gate-interleaved weights
// and swapped-operand MFMA (lane's f32x4 = {i,f,g,o} of one (b,h) cell).

#define BB  2048
#define TT  96
#define HHH 1024
#define NG  4096      // 4*H
#define KL1 1088      // 64 (x pad) + 1024 (h1)
#define KL2 2048      // h1 | h2
#define LDH 2048      // H12 row stride (bf16 elems)

typedef __bf16 bf16;
typedef __bf16 bf16x8 __attribute__((ext_vector_type(8)));
typedef float  f32x4  __attribute__((ext_vector_type(4)));

__device__ __forceinline__ float sigm(float x) { return 1.0f / (1.0f + __expf(-x)); }

__device__ __forceinline__ void gload16(const bf16* g, bf16* l) {
  __builtin_amdgcn_global_load_lds((const __attribute__((address_space(1))) void*)g,
                                   (__attribute__((address_space(3))) void*)l, 16, 0, 0);
}

// ---------------- prep kernels ----------------
// Weight rows permuted: out row n' = h*4 + gate  <-  in row gate*1024 + h.

__global__ __launch_bounds__(256) void build_w0(const float* __restrict__ Wih0,
                                                const float* __restrict__ Whh0,
                                                bf16* __restrict__ W0) {
  int idx = blockIdx.x * 256 + threadIdx.x;
  if (idx >= NG * KL1) return;
  int np = idx / KL1, k = idx % KL1;
  int n = (np & 3) * 1024 + (np >> 2);
  float v;
  if (k < 60)       v = Wih0[n * 60 + k];
  else if (k < 64)  v = 0.0f;
  else              v = Whh0[n * 1024 + (k - 64)];
  W0[idx] = (bf16)v;
}

__global__ __launch_bounds__(256) void build_w1(const float* __restrict__ Wih1,
                                                const float* __restrict__ Whh1,
                                                bf16* __restrict__ W1) {
  int idx = blockIdx.x * 256 + threadIdx.x;
  if (idx >= NG * KL2) return;
  int np = idx >> 11, k = idx & 2047;
  int n = (np & 3) * 1024 + (np >> 2);
  float v = (k < 1024) ? Wih1[n * 1024 + k] : Whh1[n * 1024 + (k - 1024)];
  W1[idx] = (bf16)v;
}

__global__ __launch_bounds__(256) void perm_bias(const float* __restrict__ b0,
                                                 const float* __restrict__ b1,
                                                 float* __restrict__ b0p,
                                                 float* __restrict__ b1p) {
  int idx = blockIdx.x * 256 + threadIdx.x;
  if (idx >= NG) return;
  int n = (idx & 3) * 1024 + (idx >> 2);
  b0p[idx] = b0[n];
  b1p[idx] = b1[n];
}

__global__ __launch_bounds__(256) void build_x(
    const float* __restrict__ dec, const float* __restrict__ ty, const float* __restrict__ lec,
    const int* __restrict__ gid, const int* __restrict__ cp, const int* __restrict__ cct,
    const int* __restrict__ cpt, const int* __restrict__ ccl,
    const float* __restrict__ gemb, const float* __restrict__ ep, const float* __restrict__ ect,
    const float* __restrict__ ept, const float* __restrict__ ecl,
    bf16* __restrict__ X) {
  int idx = blockIdx.x * 256 + threadIdx.x;  // over B*T
  if (idx >= BB * TT) return;
  int b = idx / TT, t = idx % TT;
  bf16* x = X + (size_t)idx * 64;
  x[0] = (bf16)((t == 0) ? lec[b] : ty[b * TT + t - 1]);
  const float* d = dec + (size_t)idx * 32;
  #pragma unroll
  for (int k = 0; k < 32; ++k) x[1 + k] = (bf16)d[k];
  const float* e;
  e = ep  + cp[b]  * 4;  for (int j = 0; j < 4;  ++j) x[33 + j] = (bf16)e[j];
  e = ect + cct[b] * 2;  for (int j = 0; j < 2;  ++j) x[37 + j] = (bf16)e[j];
  e = ept + cpt[b] * 3;  for (int j = 0; j < 3;  ++j) x[39 + j] = (bf16)e[j];
  e = ecl + ccl[b] * 2;  for (int j = 0; j < 2;  ++j) x[42 + j] = (bf16)e[j];
  e = gemb + gid[b] * 16; for (int j = 0; j < 16; ++j) x[44 + j] = (bf16)e[j];
  for (int j = 60; j < 64; ++j) x[j] = (bf16)0.0f;
}

__global__ __launch_bounds__(256) void init_state(const float* __restrict__ enc_h,
                                                  const float* __restrict__ enc_c,
                                                  bf16* __restrict__ H12,
                                                  float* __restrict__ c1t,
                                                  float* __restrict__ c2t) {
  int idx = blockIdx.x * 256 + threadIdx.x;  // over B*H
  if (idx >= BB * HHH) return;
  int b = idx >> 10, h = idx & 1023;
  H12[(size_t)b * LDH + h]        = (bf16)enc_h[idx];
  H12[(size_t)b * LDH + 1024 + h] = (bf16)enc_h[(size_t)BB * HHH + idx];
  c1t[(size_t)h * BB + b] = enc_c[idx];
  c2t[(size_t)h * BB + b] = enc_c[(size_t)BB * HHH + idx];
}

// ---------------- fused GEMM + cell ----------------
// gates(b, n') = A(b,:) . W(n',:), n' = h*4 + gate.
// MFMA issued as mfma(W_frag, A_frag): D rows = gate cols, D cols = batch.
// Lane holds batch = tm+wb+nb*16+(lane&15); gate col = tn+wg+mw*16+(lane>>4)*4+r.
// => per (mw,nb) the lane's f32x4 is {i,f,g,o} of one (b, h) cell.

template <int MODE>  // 0: layer1 (K=1088, A = [x|h1], writes h1); 1: layer2 (K=2048, A=H12, writes h2 + proj)
__global__ __launch_bounds__(256, 2) void gemm_cell(
    const bf16* __restrict__ Ah, const bf16* __restrict__ Ax,
    const bf16* __restrict__ Wt, const float* __restrict__ bperm,
    float* __restrict__ ct, bf16* __restrict__ H12,
    const float* __restrict__ wp, const float* __restrict__ bp,
    float* __restrict__ y, int t) {
  constexpr int KT   = (MODE == 0) ? KL1 : KL2;
  constexpr int HOFF = (MODE == 0) ? 0 : 1024;
  __shared__ alignas(16) bf16 As[128 * 32];
  __shared__ alignas(16) bf16 Ws[128 * 32];
  __shared__ alignas(16) bf16 hst[4][64 * 16];

  int tid = threadIdx.x;
  int bid = blockIdx.x;
  int swz = (bid & 7) * 64 + (bid >> 3);   // XCD-aware, bijective (512 % 8 == 0)
  int tm = (swz & 15) << 7;   // batch tile
  int tn = (swz >> 4) << 7;   // gate-col tile
  int lane = tid & 63;
  int w = tid >> 6;
  int wg = (w & 1) << 6;      // gate-dim quadrant
  int wb = (w >> 1) << 6;     // batch-dim quadrant

  f32x4 acc[4][4];
  #pragma unroll
  for (int mw = 0; mw < 4; ++mw)
    #pragma unroll
    for (int nb = 0; nb < 4; ++nb) acc[mw][nb] = (f32x4){0.f, 0.f, 0.f, 0.f};

  int r0 = tid >> 2,          kc0 = (tid & 3) << 3;
  int r1 = (256 + tid) >> 2;
  bf16* ldsA0 = &As[(tid & ~63) * 8];
  bf16* ldsA1 = &As[(256 + (tid & ~63)) * 8];
  bf16* ldsB0 = &Ws[(tid & ~63) * 8];
  bf16* ldsB1 = &Ws[(256 + (tid & ~63)) * 8];

  int lrow = lane & 15, koff = (lane >> 4) << 3;

  for (int kt = 0; kt < KT / 32; ++kt) {
    int gk0 = kt * 32 + kc0;
    const bf16 *a0, *a1;
    if constexpr (MODE == 0) {
      a0 = (gk0 < 64) ? (Ax + ((size_t)(tm + r0) * TT + t) * 64 + gk0)
                      : (Ah + (size_t)(tm + r0) * LDH + (gk0 - 64));
      a1 = (gk0 < 64) ? (Ax + ((size_t)(tm + r1) * TT + t) * 64 + gk0)
                      : (Ah + (size_t)(tm + r1) * LDH + (gk0 - 64));
    } else {
      a0 = Ah + (size_t)(tm + r0) * LDH + gk0;
      a1 = Ah + (size_t)(tm + r1) * LDH + gk0;
    }
    const bf16* b0p_ = Wt + (size_t)(tn + r0) * KT + gk0;
    const bf16* b1p_ = Wt + (size_t)(tn + r1) * KT + gk0;

    __syncthreads();
    gload16(a0, ldsA0);
    gload16(a1, ldsA1);
    gload16(b0p_, ldsB0);
    gload16(b1p_, ldsB1);
    __syncthreads();

    bf16x8 af[4], wf[4];
    #pragma unroll
    for (int nb = 0; nb < 4; ++nb)
      af[nb] = *reinterpret_cast<const bf16x8*>(&As[(wb + nb * 16 + lrow) * 32 + koff]);
    #pragma unroll
    for (int mw = 0; mw < 4; ++mw)
      wf[mw] = *reinterpret_cast<const bf16x8*>(&Ws[(wg + mw * 16 + lrow) * 32 + koff]);
    #pragma unroll
    for (int mw = 0; mw < 4; ++mw)
      #pragma unroll
      for (int nb = 0; nb < 4; ++nb)
        acc[mw][nb] = __builtin_amdgcn_mfma_f32_16x16x32_bf16(wf[mw], af[nb], acc[mw][nb], 0, 0, 0);
  }

  // ---- fused cell epilogue ----
  int u = lane >> 4;                 // 0..3 (h sub-index)
  int bl = lane & 15;                // batch sub-index
  int hwave = (tn + wg) >> 2;        // wave's global h base (0..1023)
  float yp[4] = {0.f, 0.f, 0.f, 0.f};

  #pragma unroll
  for (int mw = 0; mw < 4; ++mw) {
    int hg = hwave + mw * 4 + u;     // global h
    f32x4 bv = *reinterpret_cast<const f32x4*>(&bperm[hg * 4]);
    float wph = (MODE == 1) ? wp[hg] : 0.f;
    #pragma unroll
    for (int nb = 0; nb < 4; ++nb) {
      int bg = tm + wb + nb * 16 + bl;   // global batch
      float gi = acc[mw][nb][0] + bv[0];
      float gf = acc[mw][nb][1] + bv[1];
      float gg = acc[mw][nb][2] + bv[2];
      float go = acc[mw][nb][3] + bv[3];
      float* cp_ = ct + (size_t)hg * BB + bg;
      float c = *cp_;
      float cn = sigm(gf) * c + sigm(gi) * tanhf(gg);
      float hn = sigm(go) * tanhf(cn);
      *cp_ = cn;
      hst[w][(nb * 16 + bl) * 16 + mw * 4 + u] = (bf16)hn;
      if (MODE == 1) yp[nb] += hn * wph;
    }
  }

  asm volatile("s_waitcnt lgkmcnt(0)" ::: "memory");
  __builtin_amdgcn_sched_barrier(0);

  // coalesced H12 write-out from per-wave LDS stage (64 b x 16 h)
  #pragma unroll
  for (int q = 0; q < 2; ++q) {
    int chunk = q * 64 + lane;       // 0..127
    int bl2 = chunk >> 1, half = chunk & 1;
    bf16x8 v = *reinterpret_cast<const bf16x8*>(&hst[w][bl2 * 16 + half * 8]);
    int bg = tm + wb + bl2;
    *reinterpret_cast<bf16x8*>(&H12[(size_t)bg * LDH + HOFF + hwave + half * 8]) = v;
  }

  if constexpr (MODE == 1) {
    #pragma unroll
    for (int nb = 0; nb < 4; ++nb) {
      float s = yp[nb];
      s += __shfl_xor(s, 16);
      s += __shfl_xor(s, 32);
      if (lane < 16)
        atomicAdd(&y[(size_t)(tm + wb + nb * 16 + lane) * TT + t], s);
    }
  } else {
    // init y[:, t] = b_proj (exactly once: blocks with tn==0 cover all tm)
    if (tn == 0 && tid < 128) y[(size_t)(tm + tid) * TT + t] = bp[0];
  }
}

// ---------------- launch ----------------

extern "C" void kernel_launch(void* const* d_in, const int* in_sizes, int n_in,
                              void* d_out, int out_size, void* d_ws, size_t ws_size,
                              hipStream_t stream) {
  const float* dec   = (const float*)d_in[0];
  const float* ty    = (const float*)d_in[1];
  const float* enc_h = (const float*)d_in[2];
  const float* enc_c = (const float*)d_in[3];
  const float* lec   = (const float*)d_in[4];
  const int*   gid   = (const int*)d_in[5];
  const int*   cp    = (const int*)d_in[6];
  const int*   cct   = (const int*)d_in[7];
  const int*   cpt   = (const int*)d_in[8];
  const int*   ccl   = (const int*)d_in[9];
  const float* gemb  = (const float*)d_in[10];
  const float* ep    = (const float*)d_in[11];
  const float* ect   = (const float*)d_in[12];
  const float* ept   = (const float*)d_in[13];
  const float* ecl   = (const float*)d_in[14];
  const float* Wih0  = (const float*)d_in[15];
  const float* Whh0  = (const float*)d_in[16];
  const float* b0    = (const float*)d_in[17];
  const float* Wih1  = (const float*)d_in[18];
  const float* Whh1  = (const float*)d_in[19];
  const float* b1    = (const float*)d_in[20];
  const float* wp    = (const float*)d_in[21];
  const float* bp    = (const float*)d_in[22];
  float* y = (float*)d_out;

  char* ws = (char*)d_ws;
  bf16* W0    = (bf16*)ws;  ws += (size_t)NG * KL1 * 2;     //  8.9 MB
  bf16* W1    = (bf16*)ws;  ws += (size_t)NG * KL2 * 2;     // 16.8 MB
  bf16* X     = (bf16*)ws;  ws += (size_t)BB * TT * 64 * 2; // 25.2 MB
  bf16* H12   = (bf16*)ws;  ws += (size_t)BB * LDH * 2;     //  8.4 MB
  float* c1t  = (float*)ws; ws += (size_t)BB * HHH * 4;     //  8.4 MB
  float* c2t  = (float*)ws; ws += (size_t)BB * HHH * 4;     //  8.4 MB
  float* b0p  = (float*)ws; ws += (size_t)NG * 4;           //  16 KB
  float* b1p  = (float*)ws; ws += (size_t)NG * 4;           //  16 KB

  build_w0<<<(NG * KL1 + 255) / 256, 256, 0, stream>>>(Wih0, Whh0, W0);
  build_w1<<<(NG * KL2 + 255) / 256, 256, 0, stream>>>(Wih1, Whh1, W1);
  perm_bias<<<NG / 256, 256, 0, stream>>>(b0, b1, b0p, b1p);
  build_x<<<(BB * TT + 255) / 256, 256, 0, stream>>>(dec, ty, lec, gid, cp, cct, cpt, ccl,
                                                     gemb, ep, ect, ept, ecl, X);
  init_state<<<(BB * HHH) / 256, 256, 0, stream>>>(enc_h, enc_c, H12, c1t, c2t);

  for (int t = 0; t < TT; ++t) {
    gemm_cell<0><<<512, 256, 0, stream>>>(H12, X, W0, b0p, c1t, H12, nullptr, bp, y, t);
    gemm_cell<1><<<512, 256, 0, stream>>>(H12, nullptr, W1, b1p, c2t, H12, wp, bp, y, t);
  }
}

// Round 3
// 7136.719 us; speedup vs baseline: 1.2959x; 1.2083x over previous
//
#include <hip/hip_runtime.h>
#include <hip/hip_bf16.h>
#include <stdint.h>

// Decoder: 2-layer LSTM, B=2048, T=96, H=1024, teacher forcing=1.0.
// Round 3: dispatch D_t = {L2(t) || L1(t+1)} (1024 blocks, 4/CU), ping-pong
// h1/h2 buffers (also removes round-2 epilogue race), double-buffered LDS with
// 2-phase prefetch, both-sides XOR swizzle on LDS K-offset, 32KB LDS/block.

#define BB  2048
#define TT  96
#define NG  4096
#define KL1 1088      // 64 (x pad) + 1024 (h1)
#define KL2 2048      // h1 | h2

typedef __bf16 bf16;
typedef __bf16 bf16x8 __attribute__((ext_vector_type(8)));
typedef float  f32x4  __attribute__((ext_vector_type(4)));

__device__ __forceinline__ float sigm(float x) { return 1.0f / (1.0f + __expf(-x)); }

__device__ __forceinline__ void gload16(const bf16* g, bf16* l) {
  __builtin_amdgcn_global_load_lds((const __attribute__((address_space(1))) void*)g,
                                   (__attribute__((address_space(3))) void*)l, 16, 0, 0);
}

// ---------------- prep kernels ----------------
// Weight rows permuted: out row n' = h*4 + gate  <-  in row gate*1024 + h.

__global__ __launch_bounds__(256) void build_w0(const float* __restrict__ Wih0,
                                                const float* __restrict__ Whh0,
                                                bf16* __restrict__ W0) {
  int idx = blockIdx.x * 256 + threadIdx.x;
  if (idx >= NG * KL1) return;
  int np = idx / KL1, k = idx % KL1;
  int n = (np & 3) * 1024 + (np >> 2);
  float v;
  if (k < 60)       v = Wih0[n * 60 + k];
  else if (k < 64)  v = 0.0f;
  else              v = Whh0[n * 1024 + (k - 64)];
  W0[idx] = (bf16)v;
}

__global__ __launch_bounds__(256) void build_w1(const float* __restrict__ Wih1,
                                                const float* __restrict__ Whh1,
                                                bf16* __restrict__ W1) {
  int idx = blockIdx.x * 256 + threadIdx.x;
  if (idx >= NG * KL2) return;
  int np = idx >> 11, k = idx & 2047;
  int n = (np & 3) * 1024 + (np >> 2);
  float v = (k < 1024) ? Wih1[n * 1024 + k] : Whh1[n * 1024 + (k - 1024)];
  W1[idx] = (bf16)v;
}

__global__ __launch_bounds__(256) void perm_bias(const float* __restrict__ b0,
                                                 const float* __restrict__ b1,
                                                 float* __restrict__ b0p,
                                                 float* __restrict__ b1p) {
  int idx = blockIdx.x * 256 + threadIdx.x;
  if (idx >= NG) return;
  int n = (idx & 3) * 1024 + (idx >> 2);
  b0p[idx] = b0[n];
  b1p[idx] = b1[n];
}

__global__ __launch_bounds__(256) void build_x(
    const float* __restrict__ dec, const float* __restrict__ ty, const float* __restrict__ lec,
    const int* __restrict__ gid, const int* __restrict__ cp, const int* __restrict__ cct,
    const int* __restrict__ cpt, const int* __restrict__ ccl,
    const float* __restrict__ gemb, const float* __restrict__ ep, const float* __restrict__ ect,
    const float* __restrict__ ept, const float* __restrict__ ecl,
    bf16* __restrict__ X) {
  int idx = blockIdx.x * 256 + threadIdx.x;  // over B*T
  if (idx >= BB * TT) return;
  int b = idx / TT, t = idx % TT;
  bf16* x = X + (size_t)idx * 64;
  x[0] = (bf16)((t == 0) ? lec[b] : ty[b * TT + t - 1]);
  const float* d = dec + (size_t)idx * 32;
  #pragma unroll
  for (int k = 0; k < 32; ++k) x[1 + k] = (bf16)d[k];
  const float* e;
  e = ep  + cp[b]  * 4;  for (int j = 0; j < 4;  ++j) x[33 + j] = (bf16)e[j];
  e = ect + cct[b] * 2;  for (int j = 0; j < 2;  ++j) x[37 + j] = (bf16)e[j];
  e = ept + cpt[b] * 3;  for (int j = 0; j < 3;  ++j) x[39 + j] = (bf16)e[j];
  e = ecl + ccl[b] * 2;  for (int j = 0; j < 2;  ++j) x[42 + j] = (bf16)e[j];
  e = gemb + gid[b] * 16; for (int j = 0; j < 16; ++j) x[44 + j] = (bf16)e[j];
  for (int j = 60; j < 64; ++j) x[j] = (bf16)0.0f;
}

__global__ __launch_bounds__(256) void init_state(const float* __restrict__ enc_h,
                                                  const float* __restrict__ enc_c,
                                                  bf16* __restrict__ H1b,
                                                  bf16* __restrict__ H2b,
                                                  float* __restrict__ c1t,
                                                  float* __restrict__ c2t) {
  int idx = blockIdx.x * 256 + threadIdx.x;  // over B*H
  if (idx >= BB * 1024) return;
  int b = idx >> 10, h = idx & 1023;
  H1b[idx] = (bf16)enc_h[idx];
  H2b[idx] = (bf16)enc_h[(size_t)BB * 1024 + idx];
  c1t[(size_t)h * BB + b] = enc_c[idx];
  c2t[(size_t)h * BB + b] = enc_c[(size_t)BB * 1024 + idx];
}

// ---------------- fused GEMM + cell body ----------------
// gates(b, n') = A(b,:) . W(n',:), n' = h*4 + gate (gate-interleaved weights).
// mfma(W_frag, A_frag): lane's f32x4 = {i,f,g,o} of one (b,h) cell.
// MODE 0: A = [x(t) | h1(t-1)], K=1088, writes h1(t).
// MODE 1: A = [h1(t) | h2(t-1)], K=2048, writes h2(t) + y(t).

template <int MODE>
__device__ __forceinline__ void gemm_cell_body(
    int vb, int t,
    const bf16* __restrict__ P0, const bf16* __restrict__ P1,
    const bf16* __restrict__ Wt, const float* __restrict__ bperm,
    float* __restrict__ ct, bf16* __restrict__ Hout,
    const float* __restrict__ wp, const float* __restrict__ bp,
    float* __restrict__ y,
    bf16* As, bf16* Ws) {       // each [2][4096] elems (double-buffered 128x32)
  constexpr int KT = (MODE == 0) ? KL1 : KL2;
  constexpr int NT = KT / 32;

  int tid = threadIdx.x;
  int swz = (vb & 7) * 64 + (vb >> 3);   // XCD-aware, bijective (512 % 8 == 0)
  int tm = (swz & 15) << 7;   // batch tile
  int tn = (swz >> 4) << 7;   // gate-col tile
  int lane = tid & 63;
  int w = tid >> 6;
  int wg = (w & 1) << 6;      // gate-dim quadrant
  int wb = (w >> 1) << 6;     // batch-dim quadrant

  f32x4 acc[4][4];
  #pragma unroll
  for (int mw = 0; mw < 4; ++mw)
    #pragma unroll
    for (int nb = 0; nb < 4; ++nb) acc[mw][nb] = (f32x4){0.f, 0.f, 0.f, 0.f};

  // staging: slot s -> row = s>>2, stored k-slot (s&3); source k XOR-swizzled
  int r0 = tid >> 2, r1 = (256 + tid) >> 2;
  int kc0 = (((tid & 3) ^ (r0 & 3)) << 3);
  int kc1 = (((tid & 3) ^ (r1 & 3)) << 3);
  int dst0 = (tid & ~63) * 8;
  int dst1 = 2048 + dst0;

  auto aptr = [&](int row, int gk) -> const bf16* {
    if constexpr (MODE == 0) {
      return (gk < 64) ? (P0 + ((size_t)(tm + row) * TT + t) * 64 + gk)
                       : (P1 + (size_t)(tm + row) * 1024 + (gk - 64));
    } else {
      return (gk < 1024) ? (P0 + (size_t)(tm + row) * 1024 + gk)
                         : (P1 + (size_t)(tm + row) * 1024 + (gk - 1024));
    }
  };

  // prologue: stage kt=0 into buffer half 0
  gload16(aptr(r0, kc0), As + dst0);
  gload16(aptr(r1, kc1), As + dst1);
  gload16(Wt + (size_t)(tn + r0) * KT + kc0, Ws + dst0);
  gload16(Wt + (size_t)(tn + r1) * KT + kc1, Ws + dst1);
  __syncthreads();

  int lrow = lane & 15;
  int klocal = (((lane >> 4) ^ (lane & 3)) << 3);  // swizzled read k-offset

  for (int kt = 0; kt < NT; ++kt) {
    int cur = (kt & 1) << 12;          // 0 or 4096 elems
    if (kt + 1 < NT) {
      int nxt = 4096 - cur;
      int gk0 = (kt + 1) * 32 + kc0, gk1 = (kt + 1) * 32 + kc1;
      gload16(aptr(r0, gk0), As + nxt + dst0);
      gload16(aptr(r1, gk1), As + nxt + dst1);
      gload16(Wt + (size_t)(tn + r0) * KT + gk0, Ws + nxt + dst0);
      gload16(Wt + (size_t)(tn + r1) * KT + gk1, Ws + nxt + dst1);
    }
    __builtin_amdgcn_sched_barrier(0);  // keep prefetch issue ahead of compute

    bf16x8 af[4], wf[4];
    #pragma unroll
    for (int nb = 0; nb < 4; ++nb)
      af[nb] = *reinterpret_cast<const bf16x8*>(&As[cur + (wb + nb * 16 + lrow) * 32 + klocal]);
    #pragma unroll
    for (int mw = 0; mw < 4; ++mw)
      wf[mw] = *reinterpret_cast<const bf16x8*>(&Ws[cur + (wg + mw * 16 + lrow) * 32 + klocal]);
    #pragma unroll
    for (int mw = 0; mw < 4; ++mw)
      #pragma unroll
      for (int nb = 0; nb < 4; ++nb)
        acc[mw][nb] = __builtin_amdgcn_mfma_f32_16x16x32_bf16(wf[mw], af[nb], acc[mw][nb], 0, 0, 0);

    __syncthreads();  // drains prefetch vmcnt; next buffer ready
  }

  // ---- fused cell epilogue (hst reuses As space: all waves past final barrier) ----
  bf16* hst = As + w * 1024;          // 64 b x 16 h per wave
  int u = lane >> 4;                  // h sub-index
  int bl = lane & 15;                 // batch sub-index
  int hwave = (tn + wg) >> 2;         // wave's global h base
  float yp[4] = {0.f, 0.f, 0.f, 0.f};

  #pragma unroll
  for (int mw = 0; mw < 4; ++mw) {
    int hg = hwave + mw * 4 + u;
    f32x4 bv = *reinterpret_cast<const f32x4*>(&bperm[hg * 4]);
    float wph = 0.f;
    if constexpr (MODE == 1) wph = wp[hg];
    #pragma unroll
    for (int nb = 0; nb < 4; ++nb) {
      int bg = tm + wb + nb * 16 + bl;
      float gi = acc[mw][nb][0] + bv[0];
      float gf = acc[mw][nb][1] + bv[1];
      float gg = acc[mw][nb][2] + bv[2];
      float go = acc[mw][nb][3] + bv[3];
      float* cp_ = ct + (size_t)hg * BB + bg;
      float c = *cp_;
      float cn = sigm(gf) * c + sigm(gi) * tanhf(gg);
      float hn = sigm(go) * tanhf(cn);
      *cp_ = cn;
      hst[(nb * 16 + bl) * 16 + mw * 4 + u] = (bf16)hn;
      if constexpr (MODE == 1) yp[nb] += hn * wph;
    }
  }

  asm volatile("s_waitcnt lgkmcnt(0)" ::: "memory");
  __builtin_amdgcn_sched_barrier(0);

  // coalesced Hout write-out (LD = 1024)
  #pragma unroll
  for (int q = 0; q < 2; ++q) {
    int chunk = q * 64 + lane;
    int bl2 = chunk >> 1, half = chunk & 1;
    bf16x8 v = *reinterpret_cast<const bf16x8*>(&hst[bl2 * 16 + half * 8]);
    int bg = tm + wb + bl2;
    *reinterpret_cast<bf16x8*>(&Hout[(size_t)bg * 1024 + hwave + half * 8]) = v;
  }

  if constexpr (MODE == 1) {
    #pragma unroll
    for (int nb = 0; nb < 4; ++nb) {
      float s = yp[nb];
      s += __shfl_xor(s, 16);
      s += __shfl_xor(s, 32);
      if (lane < 16)
        atomicAdd(&y[(size_t)(tm + wb + nb * 16 + lane) * TT + t], s);
    }
  } else {
    // init y[:, t] = b_proj before D_t's layer-2 atomics (blocks with tn==0)
    if (tn == 0 && tid < 128) y[(size_t)(tm + tid) * TT + t] = bp[0];
  }
}

// D_t: blocks [0,512) do L2(t); blocks [512,1024) do L1(t+1).
// only_l1: all blocks do L1(t2+1)  (prologue, grid 512).
__global__ __launch_bounds__(256, 4) void step_kernel(
    const bf16* __restrict__ H1in, const bf16* __restrict__ H2in,
    bf16* __restrict__ H1out, bf16* __restrict__ H2out,
    const bf16* __restrict__ X,
    const bf16* __restrict__ W0, const bf16* __restrict__ W1,
    const float* __restrict__ b0p, const float* __restrict__ b1p,
    float* __restrict__ c1t, float* __restrict__ c2t,
    const float* __restrict__ wp, const float* __restrict__ bp,
    float* __restrict__ y, int t2, int only_l1) {
  __shared__ alignas(16) bf16 As[2 * 4096];
  __shared__ alignas(16) bf16 Ws[2 * 4096];
  int bid = (int)blockIdx.x;
  if (only_l1 || bid >= 512) {
    int vb = only_l1 ? bid : bid - 512;
    int t1 = t2 + 1;
    if (t1 >= TT) return;
    gemm_cell_body<0>(vb, t1, X, H1in, W0, b0p, c1t, H1out, nullptr, bp, y, As, Ws);
  } else {
    gemm_cell_body<1>(bid, t2, H1in, H2in, W1, b1p, c2t, H2out, wp, nullptr, y, As, Ws);
  }
}

// ---------------- launch ----------------

extern "C" void kernel_launch(void* const* d_in, const int* in_sizes, int n_in,
                              void* d_out, int out_size, void* d_ws, size_t ws_size,
                              hipStream_t stream) {
  const float* dec   = (const float*)d_in[0];
  const float* ty    = (const float*)d_in[1];
  const float* enc_h = (const float*)d_in[2];
  const float* enc_c = (const float*)d_in[3];
  const float* lec   = (const float*)d_in[4];
  const int*   gid   = (const int*)d_in[5];
  const int*   cp    = (const int*)d_in[6];
  const int*   cct   = (const int*)d_in[7];
  const int*   cpt   = (const int*)d_in[8];
  const int*   ccl   = (const int*)d_in[9];
  const float* gemb  = (const float*)d_in[10];
  const float* ep    = (const float*)d_in[11];
  const float* ect   = (const float*)d_in[12];
  const float* ept   = (const float*)d_in[13];
  const float* ecl   = (const float*)d_in[14];
  const float* Wih0  = (const float*)d_in[15];
  const float* Whh0  = (const float*)d_in[16];
  const float* b0    = (const float*)d_in[17];
  const float* Wih1  = (const float*)d_in[18];
  const float* Whh1  = (const float*)d_in[19];
  const float* b1    = (const float*)d_in[20];
  const float* wp    = (const float*)d_in[21];
  const float* bp    = (const float*)d_in[22];
  float* y = (float*)d_out;

  char* ws = (char*)d_ws;
  bf16* W0    = (bf16*)ws;  ws += (size_t)NG * KL1 * 2;      //  8.9 MB
  bf16* W1    = (bf16*)ws;  ws += (size_t)NG * KL2 * 2;      // 16.8 MB
  bf16* X     = (bf16*)ws;  ws += (size_t)BB * TT * 64 * 2;  // 25.2 MB
  bf16* H1a   = (bf16*)ws;  ws += (size_t)BB * 1024 * 2;     //  4.2 MB
  bf16* H1b   = (bf16*)ws;  ws += (size_t)BB * 1024 * 2;
  bf16* H2a   = (bf16*)ws;  ws += (size_t)BB * 1024 * 2;
  bf16* H2b   = (bf16*)ws;  ws += (size_t)BB * 1024 * 2;
  float* c1t  = (float*)ws; ws += (size_t)BB * 1024 * 4;     //  8.4 MB
  float* c2t  = (float*)ws; ws += (size_t)BB * 1024 * 4;     //  8.4 MB
  float* b0p  = (float*)ws; ws += (size_t)NG * 4;
  float* b1p  = (float*)ws; ws += (size_t)NG * 4;

  build_w0<<<(NG * KL1 + 255) / 256, 256, 0, stream>>>(Wih0, Whh0, W0);
  build_w1<<<(NG * KL2 + 255) / 256, 256, 0, stream>>>(Wih1, Whh1, W1);
  perm_bias<<<NG / 256, 256, 0, stream>>>(b0, b1, b0p, b1p);
  build_x<<<(BB * TT + 255) / 256, 256, 0, stream>>>(dec, ty, lec, gid, cp, cct, cpt, ccl,
                                                     gemb, ep, ect, ept, ecl, X);
  init_state<<<(BB * 1024) / 256, 256, 0, stream>>>(enc_h, enc_c, H1b, H2b, c1t, c2t);

  // prologue: L1(0) alone. h1(t) lives in H1[t&1]; h2(t) in H2[t&1].
  step_kernel<<<512, 256, 0, stream>>>(H1b, nullptr, H1a, nullptr, X, W0, W1,
                                       b0p, b1p, c1t, c2t, wp, bp, y, -1, 1);
  for (int t = 0; t < TT; ++t) {
    bf16* h1i = (t & 1) ? H1b : H1a;
    bf16* h1o = (t & 1) ? H1a : H1b;
    bf16* h2i = (t & 1) ? H2a : H2b;
    bf16* h2o = (t & 1) ? H2b : H2a;
    step_kernel<<<1024, 256, 0, stream>>>(h1i, h2i, h1o, h2o, X, W0, W1,
                                          b0p, b1p, c1t, c2t, wp, bp, y, t, 0);
  }
}